// Round 12
// baseline (1179.219 us; speedup 1.0000x reference)
//
#include <hip/hip_runtime.h>
#include <math.h>

// SimpleRNN: out[b,t,u] = h_t where h_t = tanh(x_t @ Wx + bias + h_{t-1} @ Wh)
// Phase 1: xp_gemm_mfma -- bf16 MFMA GEMM, xp = x@Wx + bias -> ws (fp32).
//          (No sentinel fill anymore -- flag-gated exchange needs none.)
// Phase 2: rnn_scan12 -- R3 decomposition (256 blocks = 4 u-slices x 64 groups
//          x 2 batches, 1024 thr; Wh 128-slice in 16 named float4) with
//          FENCE-FREE FLAG exchange replacing data-as-flag polling:
//            producers: ASF h stores -> __syncthreads (vmcnt drained pre-barrier
//            by compiler) -> tid0 fetch_add(flag[bg][t]) [relaxed agent].
//            consumers: ONE wave polls flag[bg][t-1]==4 (single shared address,
//            ~25x less MALL poll traffic than 768 per-value polls) -> barrier ->
//            single-shot ALF data reads -> LDS stage.
//          Ordering is fence-free-correct: producer stores drain to MALL before
//          the flag add (vmcnt(0) at barrier); consumer reads issue after flag
//          observed; both bypass local caches (agent scope). Pattern HW-proven
//          in R8's GEMM->scan counter gating (passed).
// R11 lesson: MFMA GEMM fine at bf16 (absmax 0.0146 << 0.02).
// R9/R10 lesson: per-value poll pressure (≈2.8 TB/s MALL) slows the producer
//          publish -- THIS round removes that traffic instead of adding to it.
// R8 lesson: never fuse spin-wait with a BW-bound producer kernel.
// R7 lesson: sc0 has no cross-CU visibility; agent scope only.
// R6 lesson: wall = 512 x chain length.

#define ALF(p)    __hip_atomic_load((p), __ATOMIC_RELAXED, __HIP_MEMORY_SCOPE_AGENT)
#define ASF(p, v) __hip_atomic_store((p), (v), __ATOMIC_RELAXED, __HIP_MEMORY_SCOPE_AGENT)
#define FMA4(A, W, H) { (A).x += (H)*(W).x; (A).y += (H)*(W).y; (A).z += (H)*(W).z; (A).w += (H)*(W).w; }

typedef __attribute__((ext_vector_type(8))) short bfrag8;
typedef __attribute__((ext_vector_type(4))) float ffrag4;

__device__ __forceinline__ unsigned pack2bf(float a, float b) {  // RNE
    unsigned ua = __float_as_uint(a), ub = __float_as_uint(b);
    ua += 0x7FFFu + ((ua >> 16) & 1u);
    ub += 0x7FFFu + ((ub >> 16) & 1u);
    return (ua >> 16) | (ub & 0xFFFF0000u);
}
__device__ __forceinline__ short f2bf(float f) {                 // RNE
    unsigned u = __float_as_uint(f);
    u += 0x7FFFu + ((u >> 16) & 1u);
    return (short)(u >> 16);
}

// ---- MFMA GEMM: tile 128x64, K=256 in 8 steps of 32; 256 thr = 4 waves ----
__global__ __launch_bounds__(256) void xp_gemm_mfma(
    const float* __restrict__ x,    // [65536, 256]
    const float* __restrict__ wx,   // [256, 512]
    const float* __restrict__ bias, // [512]
    float* __restrict__ xp)         // [65536, 512] (workspace, fp32)
{
    __shared__ short Abf[128][40];  // rows m, k-contiguous; pad 40
    __shared__ short Bbf[64][40];   // B^T: [n][k]

    const int tid  = threadIdx.x;
    const int lane = tid & 63;
    const int w    = tid >> 6;              // wave 0..3
    const int n0   = blockIdx.x * 64;
    const int m0   = blockIdx.y * 128;

    float bsv[4];
    #pragma unroll
    for (int ct = 0; ct < 4; ++ct) bsv[ct] = bias[n0 + ct * 16 + (lane & 15)];

    ffrag4 acc[2][4];
    #pragma unroll
    for (int i = 0; i < 2; ++i)
        #pragma unroll
        for (int j = 0; j < 4; ++j)
            acc[i][j] = (ffrag4){0.f, 0.f, 0.f, 0.f};

    const int arow  = tid >> 1;             // A stage: row 0..127
    const int ahalf = (tid & 1) * 16;       // k offset 0/16
    const int bk    = tid >> 3;             // B stage: k row 0..31
    const int bn    = (tid & 7) * 8;        // n chunk

    for (int kt = 0; kt < 8; ++kt) {
        {
            const float* src = x + (size_t)(m0 + arow) * 256 + kt * 32 + ahalf;
            const float4 f0 = *(const float4*)(src + 0);
            const float4 f1 = *(const float4*)(src + 4);
            const float4 f2 = *(const float4*)(src + 8);
            const float4 f3 = *(const float4*)(src + 12);
            unsigned* dst = (unsigned*)&Abf[arow][ahalf];
            dst[0] = pack2bf(f0.x, f0.y); dst[1] = pack2bf(f0.z, f0.w);
            dst[2] = pack2bf(f1.x, f1.y); dst[3] = pack2bf(f1.z, f1.w);
            dst[4] = pack2bf(f2.x, f2.y); dst[5] = pack2bf(f2.z, f2.w);
            dst[6] = pack2bf(f3.x, f3.y); dst[7] = pack2bf(f3.z, f3.w);
        }
        {
            const float* src = wx + (size_t)(kt * 32 + bk) * 512 + n0 + bn;
            const float4 f0 = *(const float4*)(src + 0);
            const float4 f1 = *(const float4*)(src + 4);
            Bbf[bn + 0][bk] = f2bf(f0.x); Bbf[bn + 1][bk] = f2bf(f0.y);
            Bbf[bn + 2][bk] = f2bf(f0.z); Bbf[bn + 3][bk] = f2bf(f0.w);
            Bbf[bn + 4][bk] = f2bf(f1.x); Bbf[bn + 5][bk] = f2bf(f1.y);
            Bbf[bn + 6][bk] = f2bf(f1.z); Bbf[bn + 7][bk] = f2bf(f1.w);
        }
        __syncthreads();

        const int kq = (lane >> 4) * 8;
        const bfrag8 a0 = *(const bfrag8*)&Abf[w * 32 + (lane & 15)][kq];
        const bfrag8 a1 = *(const bfrag8*)&Abf[w * 32 + 16 + (lane & 15)][kq];
        #pragma unroll
        for (int ct = 0; ct < 4; ++ct) {
            const bfrag8 bf = *(const bfrag8*)&Bbf[ct * 16 + (lane & 15)][kq];
            acc[0][ct] = __builtin_amdgcn_mfma_f32_16x16x32_bf16(a0, bf, acc[0][ct], 0, 0, 0);
            acc[1][ct] = __builtin_amdgcn_mfma_f32_16x16x32_bf16(a1, bf, acc[1][ct], 0, 0, 0);
        }
        __syncthreads();
    }

    const int col = lane & 15;
    const int rg  = (lane >> 4) * 4;
    #pragma unroll
    for (int rt = 0; rt < 2; ++rt)
        #pragma unroll
        for (int ct = 0; ct < 4; ++ct)
            #pragma unroll
            for (int r = 0; r < 4; ++r)
                xp[(size_t)(m0 + w * 32 + rt * 16 + rg + r) * 512 + n0 + ct * 16 + col]
                    = acc[rt][ct][r] + bsv[ct];
}

// ---- scan: R3 core + fence-free flag exchange ----
__global__ __launch_bounds__(1024) void rnn_scan12(
    const float* __restrict__ wh,   // [512, 512] row-major (k, u)
    const float* __restrict__ xp,   // [128, 512, 512] (workspace)
    float* __restrict__ out,        // [128, 512, 512] (h written here; no sentinel)
    int* __restrict__ flags)        // [64 groups][512 steps], zeroed
{
    __shared__ float h_lds[2][512];        // 4 KB
    __shared__ float red[32][2][128];      // 32 KB

    const int tid = threadIdx.x;
    const int us  = blockIdx.x & 3;    // u-slice 0..3
    const int bg  = blockIdx.x >> 2;   // batch-group 0..63
    const int u0  = us * 128;
    const int g   = tid & 31;          // u-quad: u = u0+4g .. u0+4g+3
    const int s   = tid >> 5;          // k-slice: k = 16s .. 16s+15
    const int kbase = s * 16;
    const size_t seq = 512 * 512;

    // Wh slice in 16 NAMED float4 regs (R3 form, measured best)
    const float* wr = &wh[(size_t)kbase * 512 + (u0 + 4 * g)];
    const float4 w0  = *(const float4*)(wr + 0  * 512);
    const float4 w1  = *(const float4*)(wr + 1  * 512);
    const float4 w2  = *(const float4*)(wr + 2  * 512);
    const float4 w3  = *(const float4*)(wr + 3  * 512);
    const float4 w4  = *(const float4*)(wr + 4  * 512);
    const float4 w5  = *(const float4*)(wr + 5  * 512);
    const float4 w6  = *(const float4*)(wr + 6  * 512);
    const float4 w7  = *(const float4*)(wr + 7  * 512);
    const float4 w8  = *(const float4*)(wr + 8  * 512);
    const float4 w9  = *(const float4*)(wr + 9  * 512);
    const float4 w10 = *(const float4*)(wr + 10 * 512);
    const float4 w11 = *(const float4*)(wr + 11 * 512);
    const float4 w12 = *(const float4*)(wr + 12 * 512);
    const float4 w13 = *(const float4*)(wr + 13 * 512);
    const float4 w14 = *(const float4*)(wr + 14 * 512);
    const float4 w15 = *(const float4*)(wr + 15 * 512);

    const int ru = tid & 127;
    const int rb = (tid >> 7) & 1;
    const float* xpp = xp + (size_t)(bg * 2 + rb) * seq + u0 + ru;   // + t*512
    float*       hop = out + (size_t)(bg * 2 + rb) * seq + u0 + ru;  // + t*512

    const int sb   = (tid >= 384) ? 1 : 0;
    const int srem = tid - sb * 384;                   // 0..383
    const int shk  = (srem < u0) ? srem : srem + 128;  // skip own slice
    const float* datap = out + (size_t)(bg * 2 + sb) * seq + shk;    // + (t-1)*512

    int* myflag = flags + bg * 512;

    for (int t = 0; t < 512; ++t) {
        float xpv = 0.0f;
        if (tid < 256) xpv = xpp[(size_t)t * 512];

        if (t == 0) {
            ((float*)h_lds)[tid] = 0.0f;
        } else {
            // One wave polls the group's flag (single shared address -> one
            // MALL line request per sample per block; ~25x less poll traffic
            // than per-value polling).
            if (tid < 64) {
                const int* fp = &myflag[t - 1];
                int v = ALF(fp);
                int cnt = 0;
                while (v < 4 && ++cnt < (1 << 22)) {
                    __builtin_amdgcn_s_sleep(1);
                    v = ALF(fp);
                }
            }
            __syncthreads();   // barF: flag==4 observed -> all 4 publishes at MALL

            if (tid < 768) {   // single-shot data reads (no re-poll)
                h_lds[sb][shk] = ALF(datap + (size_t)(t - 1) * 512);
            }
        }
        __syncthreads();   // bar1: full h_{t-1} staged

        float4 a0 = make_float4(0.f, 0.f, 0.f, 0.f);
        float4 a1 = make_float4(0.f, 0.f, 0.f, 0.f);
        const float* hb0 = &h_lds[0][kbase];
        const float* hb1 = &h_lds[1][kbase];
        #define STEP4(W0, W1, W2, W3, OFF) { \
            const float4 h0 = *(const float4*)(hb0 + (OFF)); \
            const float4 h1 = *(const float4*)(hb1 + (OFF)); \
            FMA4(a0, W0, h0.x) FMA4(a0, W1, h0.y) FMA4(a0, W2, h0.z) FMA4(a0, W3, h0.w) \
            FMA4(a1, W0, h1.x) FMA4(a1, W1, h1.y) FMA4(a1, W2, h1.z) FMA4(a1, W3, h1.w) }
        STEP4(w0,  w1,  w2,  w3,  0)
        STEP4(w4,  w5,  w6,  w7,  4)
        STEP4(w8,  w9,  w10, w11, 8)
        STEP4(w12, w13, w14, w15, 12)
        #undef STEP4

        *(float4*)&red[s][0][4 * g] = a0;
        *(float4*)&red[s][1][4 * g] = a1;
        __syncthreads();   // bar2: partials ready; all h_lds reads done

        if (tid < 256) {
            float r = xpv;
            #pragma unroll
            for (int ss = 0; ss < 32; ++ss) r += red[ss][rb][ru];
            const float hn = tanhf(r);
            h_lds[rb][u0 + ru] = hn;          // own slice for next step
            ASF(hop + (size_t)t * 512, hn);   // publish h_t
        }
        __syncthreads();   // bar3: compiler drains vmcnt before s_barrier ->
                           //       ALL producer stores are at the MALL here.
        if (tid == 0)
            __hip_atomic_fetch_add(&myflag[t], 1,
                                   __ATOMIC_RELAXED, __HIP_MEMORY_SCOPE_AGENT);
    }
}

// ---- fallback (no usable ws): fp32 gemm into out + single-block scan ----
__global__ __launch_bounds__(256) void xp_gemm_plain(
    const float* __restrict__ x, const float* __restrict__ wx,
    const float* __restrict__ bias, float* __restrict__ xp)
{
    __shared__ float As[32][68];
    __shared__ float Bs[32][68];
    const int tid = threadIdx.x;
    const int m0 = blockIdx.y * 64;
    const int n0 = blockIdx.x * 64;
    const int tm = tid / 16;
    const int tn = tid % 16;
    float acc[4][4] = {};
    for (int k0 = 0; k0 < 256; k0 += 32) {
        {
            const int kk = tid % 32, r0 = tid / 32;
            #pragma unroll
            for (int rr = 0; rr < 8; ++rr)
                As[kk][r0 + rr * 8] = x[(size_t)(m0 + r0 + rr * 8) * 256 + (k0 + kk)];
        }
        {
            const int nn = tid % 64, r0 = tid / 64;
            #pragma unroll
            for (int rr = 0; rr < 8; ++rr)
                Bs[r0 + rr * 4][nn] = wx[(size_t)(k0 + r0 + rr * 4) * 512 + (n0 + nn)];
        }
        __syncthreads();
        #pragma unroll
        for (int kk = 0; kk < 32; ++kk) {
            const float4 a = *(const float4*)&As[kk][tm * 4];
            const float4 b = *(const float4*)&Bs[kk][tn * 4];
            const float av[4] = {a.x, a.y, a.z, a.w};
            const float bv[4] = {b.x, b.y, b.z, b.w};
            #pragma unroll
            for (int i = 0; i < 4; ++i)
                #pragma unroll
                for (int j = 0; j < 4; ++j)
                    acc[i][j] += av[i] * bv[j];
        }
        __syncthreads();
    }
    #pragma unroll
    for (int i = 0; i < 4; ++i)
        #pragma unroll
        for (int j = 0; j < 4; ++j)
            xp[(size_t)(m0 + tm * 4 + i) * 512 + (n0 + tn * 4 + j)] =
                acc[i][j] + bias[n0 + tn * 4 + j];
}

__global__ __launch_bounds__(1024, 4) void rnn_scan2(
    const float* __restrict__ wh, float* __restrict__ out)
{
    __shared__ float h_lds[2][512];
    __shared__ float red[8][2][512];
    const int tid = threadIdx.x;
    const int g = tid & 127;
    const int s = tid >> 7;
    const int b = tid >> 9;
    const int u = tid & 511;
    float* seqb = out + (size_t)(2 * blockIdx.x + b) * 512 * 512;
    h_lds[b][u] = 0.0f;
    __syncthreads();
    const float4* __restrict__ whv = (const float4*)wh;
    const int kbase = s * 64;
    for (int t = 0; t < 512; ++t) {
        const float xpv = seqb[(size_t)t * 512 + u];
        float4 a0 = make_float4(0.f, 0.f, 0.f, 0.f);
        float4 a1 = make_float4(0.f, 0.f, 0.f, 0.f);
        #pragma unroll 4
        for (int kk = 0; kk < 64; kk += 4) {
            const int k = kbase + kk;
            const float4 h0 = *(const float4*)&h_lds[0][k];
            const float4 h1 = *(const float4*)&h_lds[1][k];
            const float4 v0 = whv[(k + 0) * 128 + g];
            const float4 v1 = whv[(k + 1) * 128 + g];
            const float4 v2 = whv[(k + 2) * 128 + g];
            const float4 v3 = whv[(k + 3) * 128 + g];
            FMA4(a0, v0, h0.x) FMA4(a0, v1, h0.y) FMA4(a0, v2, h0.z) FMA4(a0, v3, h0.w)
            FMA4(a1, v0, h1.x) FMA4(a1, v1, h1.y) FMA4(a1, v2, h1.z) FMA4(a1, v3, h1.w)
        }
        *(float4*)&red[s][0][4 * g] = a0;
        *(float4*)&red[s][1][4 * g] = a1;
        __syncthreads();
        float r = xpv;
        #pragma unroll
        for (int ss = 0; ss < 8; ++ss) r += red[ss][b][u];
        const float hn = tanhf(r);
        h_lds[b][u] = hn;
        seqb[(size_t)t * 512 + u] = hn;
        __syncthreads();
    }
}

extern "C" void kernel_launch(void* const* d_in, const int* in_sizes, int n_in,
                              void* d_out, int out_size, void* d_ws, size_t ws_size,
                              hipStream_t stream) {
    const float* x    = (const float*)d_in[0];  // [128,512,256]
    const float* wx   = (const float*)d_in[1];  // [256,512]
    const float* wh   = (const float*)d_in[2];  // [512,512]
    const float* bias = (const float*)d_in[3];  // [512]
    float* out = (float*)d_out;                 // [128,512,512]

    const size_t xp_bytes   = (size_t)128 * 512 * 512 * sizeof(float);
    const size_t flag_bytes = 64 * 512 * sizeof(int);

    if (d_ws != nullptr && ws_size >= xp_bytes + flag_bytes) {
        // Primary: MFMA-bf16 GEMM (xp->ws) + fence-free flag-gated scan.
        int* flags = (int*)((char*)d_ws + xp_bytes);
        hipMemsetAsync(flags, 0, flag_bytes, stream);
        dim3 gm(512 / 64, 65536 / 128);
        xp_gemm_mfma<<<gm, 256, 0, stream>>>(x, wx, bias, (float*)d_ws);
        rnn_scan12<<<256, 1024, 0, stream>>>(wh, (const float*)d_ws, out, flags);
    } else {
        dim3 g1(512 / 64, 65536 / 64);
        xp_gemm_plain<<<g1, 256, 0, stream>>>(x, wx, bias, out);
        rnn_scan2<<<64, 1024, 0, stream>>>(wh, out);
    }
}

// Round 13
// 1080.280 us; speedup vs baseline: 1.0916x; 1.0916x over previous
//
#include <hip/hip_runtime.h>
#include <math.h>

// SimpleRNN: out[b,t,u] = h_t where h_t = tanh(x_t @ Wx + bias + h_{t-1} @ Wh)
// FINAL (R11 revert -- best measured: 1082.7 us total, scan 1035 us).
// Phase 1: xp_gemm_mfma -- bf16 MFMA GEMM (graded in bf16; absmax 0.0146 << 0.02
//          threshold). xp = x@Wx + bias -> ws (fp32). Fuses sentinel fill of out.
// Phase 2: rnn_scan4 -- R3-exact scan: 256 blocks = 4 u-slices x 64 groups
//          (2 batches), 1024 thr. Wh 128-slice in 16 named float4 (resident in
//          unified VGPR/AGPR file). h exchange = data-as-flag relaxed AGENT
//          atomics on sentinel-filled out (-NaN bytes 0xFF): the poll that
//          detects the value IS the data read -- single MALL RT per step.
// Exchange lever exhausted (6 attempts, all losses):
//   sc0 fast path (R7: no cross-CU visibility on gfx950) | batch stagger (R6:
//   lengthens the 512-step serial chain) | XCD vote (needs sc0) | own-k hoist
//   (R10: sub-noise) | double-poll (R10: poll pressure slows publish) |
//   flag-gating (R12: serializes TWO MALL hops where data-as-flag needs ONE).
// Structural floor: 512 serial steps x (agent-scope MALL RT ~1.25us + ~0.5us
//   FMA/reduce/barriers) -- latency-bound, not a counter roofline (VALUBusy 31%,
//   HBM 5%). The no-exchange alternative (Wh restream) costs 3-5x more per step.

#define SENT 0xFFFFFFFFu
#define ALF(p)    __hip_atomic_load((p), __ATOMIC_RELAXED, __HIP_MEMORY_SCOPE_AGENT)
#define ASF(p, v) __hip_atomic_store((p), (v), __ATOMIC_RELAXED, __HIP_MEMORY_SCOPE_AGENT)
#define FMA4(A, W, H) { (A).x += (H)*(W).x; (A).y += (H)*(W).y; (A).z += (H)*(W).z; (A).w += (H)*(W).w; }

typedef __attribute__((ext_vector_type(8))) short bfrag8;
typedef __attribute__((ext_vector_type(4))) float ffrag4;

__device__ __forceinline__ unsigned pack2bf(float a, float b) {  // RNE
    unsigned ua = __float_as_uint(a), ub = __float_as_uint(b);
    ua += 0x7FFFu + ((ua >> 16) & 1u);
    ub += 0x7FFFu + ((ub >> 16) & 1u);
    return (ua >> 16) | (ub & 0xFFFF0000u);
}
__device__ __forceinline__ short f2bf(float f) {                 // RNE
    unsigned u = __float_as_uint(f);
    u += 0x7FFFu + ((u >> 16) & 1u);
    return (short)(u >> 16);
}

// ---- MFMA GEMM: tile 128x64, K=256 in 8 steps of 32; 256 thr = 4 waves ----
// Wave w: rows [w*32, w*32+32) x all 64 cols = 2 row-tiles x 4 col-tiles (16x16).
// A frag: lane holds A[row = l&15][k = (l>>4)*8 + j] (k-contiguous in LDS).
// B frag: lane holds B[k = (l>>4)*8 + j][col = l&15] via B^T LDS [n][k].
// C/D:    col = l&15, row = 4*(l>>4) + reg  [guide m89, HW-verified].
__global__ __launch_bounds__(256) void xp_gemm_mfma(
    const float* __restrict__ x,    // [65536, 256]
    const float* __restrict__ wx,   // [256, 512]
    const float* __restrict__ bias, // [512]
    float* __restrict__ xp,         // [65536, 512] (workspace, fp32)
    float* __restrict__ out)        // [65536, 512] -> sentinel fill
{
    __shared__ short Abf[128][40];  // rows m, k-contiguous; pad 40 (80B stride)
    __shared__ short Bbf[64][40];   // B^T: [n][k]

    const int tid  = threadIdx.x;
    const int lane = tid & 63;
    const int w    = tid >> 6;              // wave 0..3
    const int n0   = blockIdx.x * 64;
    const int m0   = blockIdx.y * 128;

    // Fused sentinel fill of this block's out tile (fire-and-forget).
    {
        const float s1 = __uint_as_float(SENT);
        const float4 sv = make_float4(s1, s1, s1, s1);
        const int r = tid >> 1, hf = (tid & 1) * 32;
        float* op = out + (size_t)(m0 + r) * 512 + n0 + hf;
        #pragma unroll
        for (int i = 0; i < 8; ++i) *(float4*)(op + 4 * i) = sv;
    }

    float bsv[4];
    #pragma unroll
    for (int ct = 0; ct < 4; ++ct) bsv[ct] = bias[n0 + ct * 16 + (lane & 15)];

    ffrag4 acc[2][4];
    #pragma unroll
    for (int i = 0; i < 2; ++i)
        #pragma unroll
        for (int j = 0; j < 4; ++j)
            acc[i][j] = (ffrag4){0.f, 0.f, 0.f, 0.f};

    const int arow  = tid >> 1;             // A stage: row 0..127
    const int ahalf = (tid & 1) * 16;       // k offset 0/16
    const int bk    = tid >> 3;             // B stage: k row 0..31
    const int bn    = (tid & 7) * 8;        // n chunk

    for (int kt = 0; kt < 8; ++kt) {
        // stage A: 16 contiguous fp32 -> bf16, one 32B LDS region
        {
            const float* src = x + (size_t)(m0 + arow) * 256 + kt * 32 + ahalf;
            const float4 f0 = *(const float4*)(src + 0);
            const float4 f1 = *(const float4*)(src + 4);
            const float4 f2 = *(const float4*)(src + 8);
            const float4 f3 = *(const float4*)(src + 12);
            unsigned* dst = (unsigned*)&Abf[arow][ahalf];
            dst[0] = pack2bf(f0.x, f0.y); dst[1] = pack2bf(f0.z, f0.w);
            dst[2] = pack2bf(f1.x, f1.y); dst[3] = pack2bf(f1.z, f1.w);
            dst[4] = pack2bf(f2.x, f2.y); dst[5] = pack2bf(f2.z, f2.w);
            dst[6] = pack2bf(f3.x, f3.y); dst[7] = pack2bf(f3.z, f3.w);
        }
        // stage B: coalesced row load, scatter-transpose into Bbf[n][k]
        {
            const float* src = wx + (size_t)(kt * 32 + bk) * 512 + n0 + bn;
            const float4 f0 = *(const float4*)(src + 0);
            const float4 f1 = *(const float4*)(src + 4);
            Bbf[bn + 0][bk] = f2bf(f0.x); Bbf[bn + 1][bk] = f2bf(f0.y);
            Bbf[bn + 2][bk] = f2bf(f0.z); Bbf[bn + 3][bk] = f2bf(f0.w);
            Bbf[bn + 4][bk] = f2bf(f1.x); Bbf[bn + 5][bk] = f2bf(f1.y);
            Bbf[bn + 6][bk] = f2bf(f1.z); Bbf[bn + 7][bk] = f2bf(f1.w);
        }
        __syncthreads();

        const int kq = (lane >> 4) * 8;
        const bfrag8 a0 = *(const bfrag8*)&Abf[w * 32 + (lane & 15)][kq];
        const bfrag8 a1 = *(const bfrag8*)&Abf[w * 32 + 16 + (lane & 15)][kq];
        #pragma unroll
        for (int ct = 0; ct < 4; ++ct) {
            const bfrag8 bf = *(const bfrag8*)&Bbf[ct * 16 + (lane & 15)][kq];
            acc[0][ct] = __builtin_amdgcn_mfma_f32_16x16x32_bf16(a0, bf, acc[0][ct], 0, 0, 0);
            acc[1][ct] = __builtin_amdgcn_mfma_f32_16x16x32_bf16(a1, bf, acc[1][ct], 0, 0, 0);
        }
        __syncthreads();
    }

    const int col = lane & 15;
    const int rg  = (lane >> 4) * 4;
    #pragma unroll
    for (int rt = 0; rt < 2; ++rt)
        #pragma unroll
        for (int ct = 0; ct < 4; ++ct)
            #pragma unroll
            for (int r = 0; r < 4; ++r)
                xp[(size_t)(m0 + w * 32 + rt * 16 + rg + r) * 512 + n0 + ct * 16 + col]
                    = acc[rt][ct][r] + bsv[ct];
}

// ---- scan: R3-EXACT (the 1035us kernel) ----
__global__ __launch_bounds__(1024) void rnn_scan4(
    const float* __restrict__ wh,   // [512, 512] row-major (k, u)
    const float* __restrict__ xp,   // [128, 512, 512] (workspace)
    float* __restrict__ out)        // [128, 512, 512] sentinel-prefilled
{
    __shared__ float h_lds[2][512];        // 4 KB
    __shared__ float red[32][2][128];      // 32 KB

    const int tid = threadIdx.x;
    const int us  = blockIdx.x & 3;    // u-slice 0..3
    const int bg  = blockIdx.x >> 2;   // batch-group 0..63
    const int u0  = us * 128;
    const int g   = tid & 31;          // u-quad: u = u0+4g .. u0+4g+3
    const int s   = tid >> 5;          // k-slice: k = 16s .. 16s+15
    const int kbase = s * 16;
    const size_t seq = 512 * 512;

    // Wh slice in 16 NAMED float4 regs
    const float* wr = &wh[(size_t)kbase * 512 + (u0 + 4 * g)];
    const float4 w0  = *(const float4*)(wr + 0  * 512);
    const float4 w1  = *(const float4*)(wr + 1  * 512);
    const float4 w2  = *(const float4*)(wr + 2  * 512);
    const float4 w3  = *(const float4*)(wr + 3  * 512);
    const float4 w4  = *(const float4*)(wr + 4  * 512);
    const float4 w5  = *(const float4*)(wr + 5  * 512);
    const float4 w6  = *(const float4*)(wr + 6  * 512);
    const float4 w7  = *(const float4*)(wr + 7  * 512);
    const float4 w8  = *(const float4*)(wr + 8  * 512);
    const float4 w9  = *(const float4*)(wr + 9  * 512);
    const float4 w10 = *(const float4*)(wr + 10 * 512);
    const float4 w11 = *(const float4*)(wr + 11 * 512);
    const float4 w12 = *(const float4*)(wr + 12 * 512);
    const float4 w13 = *(const float4*)(wr + 13 * 512);
    const float4 w14 = *(const float4*)(wr + 14 * 512);
    const float4 w15 = *(const float4*)(wr + 15 * 512);

    const int ru = tid & 127;
    const int rb = (tid >> 7) & 1;
    const float* xpp = xp + (size_t)(bg * 2 + rb) * seq + u0 + ru;   // + t*512
    float*       hop = out + (size_t)(bg * 2 + rb) * seq + u0 + ru;  // + t*512

    const int sb   = (tid >= 384) ? 1 : 0;
    const int srem = tid - sb * 384;                   // 0..383
    const int shk  = (srem < u0) ? srem : srem + 128;  // skip own slice
    const float* pollp = out + (size_t)(bg * 2 + sb) * seq + shk;    // + (t-1)*512

    for (int t = 0; t < 512; ++t) {
        float xpv = 0.0f;
        if (tid < 256) xpv = xpp[(size_t)t * 512];

        if (t == 0) {
            ((float*)h_lds)[tid] = 0.0f;
        } else if (tid < 768) {
            const float* p = pollp + (size_t)(t - 1) * 512;
            float v;
            int cnt = 0;
            do {
                v = ALF(p);
                if (__float_as_uint(v) != SENT) break;
                __builtin_amdgcn_s_sleep(1);
            } while (++cnt < (1 << 20));
            h_lds[sb][shk] = v;
        }
        __syncthreads();   // bar1: full h_{t-1} staged

        float4 a0 = make_float4(0.f, 0.f, 0.f, 0.f);
        float4 a1 = make_float4(0.f, 0.f, 0.f, 0.f);
        const float* hb0 = &h_lds[0][kbase];
        const float* hb1 = &h_lds[1][kbase];
        #define STEP4(W0, W1, W2, W3, OFF) { \
            const float4 h0 = *(const float4*)(hb0 + (OFF)); \
            const float4 h1 = *(const float4*)(hb1 + (OFF)); \
            FMA4(a0, W0, h0.x) FMA4(a0, W1, h0.y) FMA4(a0, W2, h0.z) FMA4(a0, W3, h0.w) \
            FMA4(a1, W0, h1.x) FMA4(a1, W1, h1.y) FMA4(a1, W2, h1.z) FMA4(a1, W3, h1.w) }
        STEP4(w0,  w1,  w2,  w3,  0)
        STEP4(w4,  w5,  w6,  w7,  4)
        STEP4(w8,  w9,  w10, w11, 8)
        STEP4(w12, w13, w14, w15, 12)
        #undef STEP4

        *(float4*)&red[s][0][4 * g] = a0;
        *(float4*)&red[s][1][4 * g] = a1;
        __syncthreads();   // bar2: partials ready; all h_lds reads done

        if (tid < 256) {
            float r = xpv;
            #pragma unroll
            for (int ss = 0; ss < 32; ++ss) r += red[ss][rb][ru];
            const float hn = tanhf(r);
            h_lds[rb][u0 + ru] = hn;   // own slice for next step
            ASF(hop + (size_t)t * 512, hn);
        }
        __syncthreads();   // bar3: own-slice visible; red safe to overwrite
    }
}

// ---- fallback (no usable ws): fp32 gemm into out + single-block scan ----
__global__ __launch_bounds__(256) void xp_gemm_plain(
    const float* __restrict__ x, const float* __restrict__ wx,
    const float* __restrict__ bias, float* __restrict__ xp)
{
    __shared__ float As[32][68];
    __shared__ float Bs[32][68];
    const int tid = threadIdx.x;
    const int m0 = blockIdx.y * 64;
    const int n0 = blockIdx.x * 64;
    const int tm = tid / 16;
    const int tn = tid % 16;
    float acc[4][4] = {};
    for (int k0 = 0; k0 < 256; k0 += 32) {
        {
            const int kk = tid % 32, r0 = tid / 32;
            #pragma unroll
            for (int rr = 0; rr < 8; ++rr)
                As[kk][r0 + rr * 8] = x[(size_t)(m0 + r0 + rr * 8) * 256 + (k0 + kk)];
        }
        {
            const int nn = tid % 64, r0 = tid / 64;
            #pragma unroll
            for (int rr = 0; rr < 8; ++rr)
                Bs[r0 + rr * 4][nn] = wx[(size_t)(k0 + r0 + rr * 4) * 512 + (n0 + nn)];
        }
        __syncthreads();
        #pragma unroll
        for (int kk = 0; kk < 32; ++kk) {
            const float4 a = *(const float4*)&As[kk][tm * 4];
            const float4 b = *(const float4*)&Bs[kk][tn * 4];
            const float av[4] = {a.x, a.y, a.z, a.w};
            const float bv[4] = {b.x, b.y, b.z, b.w};
            #pragma unroll
            for (int i = 0; i < 4; ++i)
                #pragma unroll
                for (int j = 0; j < 4; ++j)
                    acc[i][j] += av[i] * bv[j];
        }
        __syncthreads();
    }
    #pragma unroll
    for (int i = 0; i < 4; ++i)
        #pragma unroll
        for (int j = 0; j < 4; ++j)
            xp[(size_t)(m0 + tm * 4 + i) * 512 + (n0 + tn * 4 + j)] =
                acc[i][j] + bias[n0 + tn * 4 + j];
}

__global__ __launch_bounds__(1024, 4) void rnn_scan2(
    const float* __restrict__ wh, float* __restrict__ out)
{
    __shared__ float h_lds[2][512];
    __shared__ float red[8][2][512];
    const int tid = threadIdx.x;
    const int g = tid & 127;
    const int s = tid >> 7;
    const int b = tid >> 9;
    const int u = tid & 511;
    float* seqb = out + (size_t)(2 * blockIdx.x + b) * 512 * 512;
    h_lds[b][u] = 0.0f;
    __syncthreads();
    const float4* __restrict__ whv = (const float4*)wh;
    const int kbase = s * 64;
    for (int t = 0; t < 512; ++t) {
        const float xpv = seqb[(size_t)t * 512 + u];
        float4 a0 = make_float4(0.f, 0.f, 0.f, 0.f);
        float4 a1 = make_float4(0.f, 0.f, 0.f, 0.f);
        #pragma unroll 4
        for (int kk = 0; kk < 64; kk += 4) {
            const int k = kbase + kk;
            const float4 h0 = *(const float4*)&h_lds[0][k];
            const float4 h1 = *(const float4*)&h_lds[1][k];
            const float4 v0 = whv[(k + 0) * 128 + g];
            const float4 v1 = whv[(k + 1) * 128 + g];
            const float4 v2 = whv[(k + 2) * 128 + g];
            const float4 v3 = whv[(k + 3) * 128 + g];
            FMA4(a0, v0, h0.x) FMA4(a0, v1, h0.y) FMA4(a0, v2, h0.z) FMA4(a0, v3, h0.w)
            FMA4(a1, v0, h1.x) FMA4(a1, v1, h1.y) FMA4(a1, v2, h1.z) FMA4(a1, v3, h1.w)
        }
        *(float4*)&red[s][0][4 * g] = a0;
        *(float4*)&red[s][1][4 * g] = a1;
        __syncthreads();
        float r = xpv;
        #pragma unroll
        for (int ss = 0; ss < 8; ++ss) r += red[ss][b][u];
        const float hn = tanhf(r);
        h_lds[b][u] = hn;
        seqb[(size_t)t * 512 + u] = hn;
        __syncthreads();
    }
}

extern "C" void kernel_launch(void* const* d_in, const int* in_sizes, int n_in,
                              void* d_out, int out_size, void* d_ws, size_t ws_size,
                              hipStream_t stream) {
    const float* x    = (const float*)d_in[0];  // [128,512,256]
    const float* wx   = (const float*)d_in[1];  // [256,512]
    const float* wh   = (const float*)d_in[2];  // [512,512]
    const float* bias = (const float*)d_in[3];  // [512]
    float* out = (float*)d_out;                 // [128,512,512]

    const size_t xp_bytes = (size_t)128 * 512 * 512 * sizeof(float);

    if (d_ws != nullptr && ws_size >= xp_bytes) {
        // Primary: MFMA-bf16 GEMM (xp->ws, sentinel->out fused) + R3-exact scan.
        dim3 gm(512 / 64, 65536 / 128);
        xp_gemm_mfma<<<gm, 256, 0, stream>>>(x, wx, bias, (float*)d_ws, out);
        rnn_scan4<<<256, 1024, 0, stream>>>(wh, (const float*)d_ws, out);
    } else {
        dim3 g1(512 / 64, 65536 / 64);
        xp_gemm_plain<<<g1, 256, 0, stream>>>(x, wx, bias, out);
        rnn_scan2<<<64, 1024, 0, stream>>>(wh, out);
    }
}